// Round 8
// baseline (754.523 us; speedup 1.0000x reference)
//
#include <hip/hip_runtime.h>
#include <hip/hip_bf16.h>

typedef __attribute__((ext_vector_type(8))) short bf16x8;
typedef __attribute__((ext_vector_type(4))) float f32x4;

__device__ __forceinline__ unsigned short f2bf(float f) {
    unsigned u = __float_as_uint(f);
    unsigned r = (u + 0x7FFFu + ((u >> 16) & 1u)) >> 16;  // RNE
    return (unsigned short)r;
}
__device__ __forceinline__ float bf2f(unsigned short b) {
    return __uint_as_float(((unsigned)b) << 16);
}
__device__ __forceinline__ unsigned pack2(float a, float b) {
    return (unsigned)f2bf(a) | ((unsigned)f2bf(b) << 16);
}
__device__ __forceinline__ unsigned pksub(unsigned a, unsigned b) {
    float r0 = bf2f((unsigned short)(a & 0xffff)) - bf2f((unsigned short)(b & 0xffff));
    float r1 = bf2f((unsigned short)(a >> 16))    - bf2f((unsigned short)(b >> 16));
    return pack2(r0, r1);
}
#define EXP2(x) __builtin_amdgcn_exp2f(x)

__device__ __forceinline__ void gload_lds16(const void* g, void* l) {
    __builtin_amdgcn_global_load_lds(
        (const __attribute__((address_space(1))) unsigned int*)g,
        (__attribute__((address_space(3))) unsigned int*)l,
        16, 0, 0);
}

// ---------------------------------------------------------------------------
// gemm_q512: qkt[M x 512](bf16) = A[M x 128](bf16) @ McatT + cbias.
// ---------------------------------------------------------------------------
__global__ __launch_bounds__(512, 2) void gemm_q512(
    const unsigned short* __restrict__ A, const unsigned short* __restrict__ WT,
    const float* __restrict__ bias, unsigned short* __restrict__ out, int M)
{
    __shared__ __align__(16) unsigned short As[64 * 128];

    const int t = threadIdx.x, wave = t >> 6, lane = t & 63;
    const int lr = lane & 15, lk = lane >> 4;

    bf16x8 Bf[4][4];
    f32x4 bs[4];
#pragma unroll
    for (int fn = 0; fn < 4; fn++) {
        const int col0 = wave * 64 + fn * 16 + lk * 4;
        bs[fn] = *reinterpret_cast<const f32x4*>(bias + col0);
        const int n = wave * 64 + fn * 16 + lr;
#pragma unroll
        for (int kk = 0; kk < 4; kk++)
            Bf[kk][fn] = *reinterpret_cast<const bf16x8*>(WT + n * 128 + kk * 32 + lk * 8);
    }

    const int row0 = blockIdx.x * 64;
#pragma unroll
    for (int i = 0; i < 2; i++) {
        const int flat = (i * 512 + t) * 16;
        const int r = flat >> 8, c = (flat >> 4) & 15;
        int gr = row0 + r; if (gr >= M) gr = M - 1;
        const void* g = A + (size_t)gr * 128 + ((c ^ (r & 7)) << 3);
        void* l = (void*)((char*)&As[0] + (size_t)(i * 512 + wave * 64) * 16 + 0);
        gload_lds16(g, l);
    }
    __syncthreads();

    f32x4 acc[4][4];
#pragma unroll
    for (int a = 0; a < 4; a++)
#pragma unroll
        for (int b = 0; b < 4; b++) acc[a][b] = (f32x4){0.f, 0.f, 0.f, 0.f};

#pragma unroll
    for (int kk = 0; kk < 4; kk++) {
        bf16x8 af[4];
#pragma unroll
        for (int fm = 0; fm < 4; fm++) {
            const int r = fm * 16 + lr;
            const int c = (kk * 4 + lk) ^ (r & 7);
            af[fm] = *reinterpret_cast<const bf16x8*>(&As[r * 128 + c * 8]);
        }
#pragma unroll
        for (int fm = 0; fm < 4; fm++)
#pragma unroll
            for (int fn = 0; fn < 4; fn++)
                acc[fm][fn] = __builtin_amdgcn_mfma_f32_16x16x32_bf16(
                    Bf[kk][fn], af[fm], acc[fm][fn], 0, 0, 0);
    }

#pragma unroll
    for (int fm = 0; fm < 4; fm++) {
        const int row = row0 + fm * 16 + lr;
        if (row < M) {
#pragma unroll
            for (int fn = 0; fn < 4; fn++) {
                const int col0 = wave * 64 + fn * 16 + lk * 4;
                f32x4 vv = acc[fm][fn] + bs[fn];
                uint2 o; o.x = pack2(vv[0], vv[1]); o.y = pack2(vv[2], vv[3]);
                *reinterpret_cast<uint2*>(out + (size_t)row * 512 + col0) = o;
            }
        }
    }
}

// ---------------------------------------------------------------------------
// gemm_k512: f_h[M x 128](fp32) += A[M x 512](bf16) @ PcatT + bias2;
// also emits f_hb bf16.
// ---------------------------------------------------------------------------
__global__ __launch_bounds__(256, 2) void gemm_k512(
    const unsigned short* __restrict__ A, const unsigned short* __restrict__ WT,
    const float* __restrict__ bias, float* __restrict__ f_h,
    unsigned short* __restrict__ f_hb, int M)
{
    __shared__ __align__(16) unsigned short As[64 * 512];  // 64KB

    const int t = threadIdx.x, wave = t >> 6, lane = t & 63;
    const int lr = lane & 15, lk = lane >> 4;

    bf16x8 Bf[16][2];
    f32x4 bs[2];
#pragma unroll
    for (int fn = 0; fn < 2; fn++) {
        const int col0 = wave * 32 + fn * 16 + lk * 4;
        bs[fn] = *reinterpret_cast<const f32x4*>(bias + col0);
        const int n = wave * 32 + fn * 16 + lr;
#pragma unroll
        for (int kk = 0; kk < 16; kk++)
            Bf[kk][fn] = *reinterpret_cast<const bf16x8*>(WT + n * 512 + kk * 32 + lk * 8);
    }

    const int row0 = blockIdx.x * 64;
#pragma unroll
    for (int i = 0; i < 16; i++) {
        const int flat = (i * 256 + t) * 16;
        const int r = flat >> 10, c = (flat >> 4) & 63;
        int gr = row0 + r; if (gr >= M) gr = M - 1;
        const void* g = A + (size_t)gr * 512 + ((c ^ (r & 7)) << 3);
        void* l = (void*)((char*)&As[0] + (size_t)(i * 256 + wave * 64) * 16);
        gload_lds16(g, l);
    }
    __syncthreads();

    f32x4 acc[4][2];
#pragma unroll
    for (int a = 0; a < 4; a++)
#pragma unroll
        for (int b = 0; b < 2; b++) acc[a][b] = (f32x4){0.f, 0.f, 0.f, 0.f};

#pragma unroll
    for (int kk = 0; kk < 16; kk++) {
        bf16x8 af[4];
#pragma unroll
        for (int fm = 0; fm < 4; fm++) {
            const int r = fm * 16 + lr;
            const int c = (kk * 4 + lk) ^ (r & 7);
            af[fm] = *reinterpret_cast<const bf16x8*>(&As[r * 512 + c * 8]);
        }
#pragma unroll
        for (int fm = 0; fm < 4; fm++)
#pragma unroll
            for (int fn = 0; fn < 2; fn++)
                acc[fm][fn] = __builtin_amdgcn_mfma_f32_16x16x32_bf16(
                    Bf[kk][fn], af[fm], acc[fm][fn], 0, 0, 0);
    }

#pragma unroll
    for (int fm = 0; fm < 4; fm++) {
        const int row = row0 + fm * 16 + lr;
        if (row < M) {
#pragma unroll
            for (int fn = 0; fn < 2; fn++) {
                const int col0 = wave * 32 + fn * 16 + lk * 4;
                const size_t off = (size_t)row * 128 + col0;
                f32x4 vv = acc[fm][fn] + bs[fn];
                vv += *reinterpret_cast<const f32x4*>(f_h + off);
                *reinterpret_cast<f32x4*>(f_h + off) = vv;
                uint2 o; o.x = pack2(vv[0], vv[1]); o.y = pack2(vv[2], vv[3]);
                *reinterpret_cast<uint2*>(f_hb + off) = o;
            }
        }
    }
}

// ---------------------------------------------------------------------------
// gemm_mrelu: h' = relu(x + (f_hb[src[e]] - h[e^1]) @ Wm + b). Reg-staged,
// edge-order output only. 5 blocks/CU (LDS-limited) for gather-latency hiding.
// ---------------------------------------------------------------------------
__global__ __launch_bounds__(256, 5) void gemm_mrelu(
    const unsigned short* __restrict__ f_hb, const unsigned short* __restrict__ h,
    const int* __restrict__ src, const unsigned short* __restrict__ WT,
    const float* __restrict__ bias, const unsigned short* __restrict__ resx,
    unsigned short* __restrict__ out, int E, int ntiles)
{
    __shared__ __align__(16) unsigned short As[2][64 * 128];

    const int t = threadIdx.x, wave = t >> 6, lane = t & 63;
    const int lr = lane & 15, lk = lane >> 4;

    bf16x8 Bf[4][2];
    f32x4 bs[2];
#pragma unroll
    for (int fn = 0; fn < 2; fn++) {
        const int col0 = wave * 32 + fn * 16 + lk * 4;
        bs[fn] = *reinterpret_cast<const f32x4*>(bias + col0);
        const int n = wave * 32 + fn * 16 + lr;
#pragma unroll
        for (int kk = 0; kk < 4; kk++)
            Bf[kk][fn] = *reinterpret_cast<const bf16x8*>(WT + n * 128 + kk * 32 + lk * 8);
    }

    uint4 Lh[4], Lf[4];
    auto load_t = [&](int row0) {
#pragma unroll
        for (int i = 0; i < 4; i++) {
            const int flat = (wave * 4 + i) * 1024 + lane * 16;
            const int r = flat >> 8, c = (flat >> 4) & 15;
            int e = row0 + r; if (e >= E) e = E - 1;
            Lh[i] = *reinterpret_cast<const uint4*>(h + (size_t)(e ^ 1) * 128 + c * 8);
            const int se = src[e];
            Lf[i] = *reinterpret_cast<const uint4*>(f_hb + (size_t)se * 128 + c * 8);
        }
    };
    auto write_t = [&](int buf) {
#pragma unroll
        for (int i = 0; i < 4; i++) {
            const int flat = (wave * 4 + i) * 1024 + lane * 16;
            const int r = flat >> 8, c = (flat >> 4) & 15;
            uint4 d;
            d.x = pksub(Lf[i].x, Lh[i].x); d.y = pksub(Lf[i].y, Lh[i].y);
            d.z = pksub(Lf[i].z, Lh[i].z); d.w = pksub(Lf[i].w, Lh[i].w);
            *reinterpret_cast<uint4*>(&As[buf][r * 128 + ((c ^ (r & 7)) << 3)]) = d;
        }
    };

    int tt = blockIdx.x;
    if (tt >= ntiles) return;
    load_t(tt * 64);
    write_t(0);
    int cur = 0;
    __syncthreads();

    for (; tt < ntiles; tt += gridDim.x) {
        const int nxt = tt + gridDim.x;
        if (nxt < ntiles) load_t(nxt * 64);

        f32x4 acc[4][2];
#pragma unroll
        for (int a = 0; a < 4; a++)
#pragma unroll
            for (int b = 0; b < 2; b++) acc[a][b] = (f32x4){0.f, 0.f, 0.f, 0.f};

#pragma unroll
        for (int kk = 0; kk < 4; kk++) {
            bf16x8 af[4];
#pragma unroll
            for (int fm = 0; fm < 4; fm++) {
                const int r = fm * 16 + lr;
                const int c = (kk * 4 + lk) ^ (r & 7);
                af[fm] = *reinterpret_cast<const bf16x8*>(&As[cur][r * 128 + c * 8]);
            }
#pragma unroll
            for (int fm = 0; fm < 4; fm++)
#pragma unroll
                for (int fn = 0; fn < 2; fn++)
                    acc[fm][fn] = __builtin_amdgcn_mfma_f32_16x16x32_bf16(
                        Bf[kk][fn], af[fm], acc[fm][fn], 0, 0, 0);
        }

        const int row0 = tt * 64;
#pragma unroll
        for (int fm = 0; fm < 4; fm++) {
            const int row = row0 + fm * 16 + lr;
            if (row < E) {
#pragma unroll
                for (int fn = 0; fn < 2; fn++) {
                    const int col0 = wave * 32 + fn * 16 + lk * 4;
                    const size_t off = (size_t)row * 128 + col0;
                    f32x4 vv = acc[fm][fn] + bs[fn];
                    uint2 rb = *reinterpret_cast<const uint2*>(resx + off);
                    vv[0] += bf2f((unsigned short)(rb.x & 0xffff));
                    vv[1] += bf2f((unsigned short)(rb.x >> 16));
                    vv[2] += bf2f((unsigned short)(rb.y & 0xffff));
                    vv[3] += bf2f((unsigned short)(rb.y >> 16));
                    vv[0] = fmaxf(vv[0], 0.f); vv[1] = fmaxf(vv[1], 0.f);
                    vv[2] = fmaxf(vv[2], 0.f); vv[3] = fmaxf(vv[3], 0.f);
                    uint2 o; o.x = pack2(vv[0], vv[1]); o.y = pack2(vv[2], vv[3]);
                    *reinterpret_cast<uint2*>(out + off) = o;
                }
            }
        }

        if (nxt < ntiles) write_t(cur ^ 1);
        __syncthreads();
        cur ^= 1;
    }
}

// ---------------------------------------------------------------------------
// gemm_final: out[M x 128](fp32) = [A0|A1|A2] @ [W0;W1;W2] + bias. One shot.
// ---------------------------------------------------------------------------
__global__ __launch_bounds__(256, 2) void gemm_final(
    const unsigned short* __restrict__ A0, const unsigned short* __restrict__ A1,
    const unsigned short* __restrict__ A2,
    const unsigned short* __restrict__ W0T, const unsigned short* __restrict__ W1T,
    const unsigned short* __restrict__ W2T,
    const float* __restrict__ bias, float* __restrict__ out, int M)
{
    __shared__ __align__(16) unsigned short As[3][64 * 128];  // 48KB

    const int t = threadIdx.x, wave = t >> 6, lane = t & 63;
    const int lr = lane & 15, lk = lane >> 4;

    const unsigned short* Asrc[3] = { A0, A1, A2 };
    const unsigned short* Wsrc[3] = { W0T, W1T, W2T };

    bf16x8 Bf[12][2];
    f32x4 bs[2];
#pragma unroll
    for (int fn = 0; fn < 2; fn++) {
        const int col0 = wave * 32 + fn * 16 + lk * 4;
        bs[fn] = *reinterpret_cast<const f32x4*>(bias + col0);
        const int n = wave * 32 + fn * 16 + lr;
#pragma unroll
        for (int b = 0; b < 3; b++)
#pragma unroll
            for (int kk = 0; kk < 4; kk++)
                Bf[b * 4 + kk][fn] = *reinterpret_cast<const bf16x8*>(
                    Wsrc[b] + n * 128 + kk * 32 + lk * 8);
    }

    const int row0 = blockIdx.x * 64;
#pragma unroll
    for (int b = 0; b < 3; b++) {
#pragma unroll
        for (int i = 0; i < 4; i++) {
            const int flat = (wave * 4 + i) * 1024 + lane * 16;
            const int r = flat >> 8, c = (flat >> 4) & 15;
            int gr = row0 + r; if (gr >= M) gr = M - 1;
            const void* g = Asrc[b] + (size_t)gr * 128 + ((c ^ (r & 7)) << 3);
            void* l = (void*)((char*)&As[b][0] + (size_t)(wave * 4 + i) * 1024);
            gload_lds16(g, l);
        }
    }
    __syncthreads();

    f32x4 acc[4][2];
#pragma unroll
    for (int a = 0; a < 4; a++)
#pragma unroll
        for (int b = 0; b < 2; b++) acc[a][b] = (f32x4){0.f, 0.f, 0.f, 0.f};

#pragma unroll
    for (int b = 0; b < 3; b++) {
#pragma unroll
        for (int kk = 0; kk < 4; kk++) {
            bf16x8 af[4];
#pragma unroll
            for (int fm = 0; fm < 4; fm++) {
                const int r = fm * 16 + lr;
                const int c = (kk * 4 + lk) ^ (r & 7);
                af[fm] = *reinterpret_cast<const bf16x8*>(&As[b][r * 128 + c * 8]);
            }
#pragma unroll
            for (int fm = 0; fm < 4; fm++)
#pragma unroll
                for (int fn = 0; fn < 2; fn++)
                    acc[fm][fn] = __builtin_amdgcn_mfma_f32_16x16x32_bf16(
                        Bf[b * 4 + kk][fn], af[fm], acc[fm][fn], 0, 0, 0);
        }
    }

#pragma unroll
    for (int fm = 0; fm < 4; fm++) {
        const int row = row0 + fm * 16 + lr;
        if (row < M) {
#pragma unroll
            for (int fn = 0; fn < 2; fn++) {
                const int col0 = wave * 32 + fn * 16 + lk * 4;
                *reinterpret_cast<f32x4*>(out + (size_t)row * 128 + col0) =
                    acc[fm][fn] + bs[fn];
            }
        }
    }
}

// ---------------------------------------------------------------------------
// CSR build
// ---------------------------------------------------------------------------
__global__ void hist_kernel(const int* __restrict__ dst, int* __restrict__ deg, int E_) {
    int e = blockIdx.x * 256 + threadIdx.x;
    if (e < E_) atomicAdd(&deg[dst[e]], 1);
}

__global__ __launch_bounds__(1024) void scan_kernel(
    const int* __restrict__ deg, int* __restrict__ rowptr,
    int* __restrict__ cursor, int N_)
{
    __shared__ int part[1024];
    const int t = threadIdx.x;
    const int chunk = (N_ + 1023) >> 10;
    const int base = t * chunk;
    int s = 0;
    for (int i = 0; i < chunk; i++) {
        int idx = base + i;
        if (idx < N_) s += deg[idx];
    }
    part[t] = s;
    __syncthreads();
    for (int off = 1; off < 1024; off <<= 1) {
        int v = (t >= off) ? part[t - off] : 0;
        __syncthreads();
        part[t] += v;
        __syncthreads();
    }
    int run = (t == 0) ? 0 : part[t - 1];
    for (int i = 0; i < chunk; i++) {
        int idx = base + i;
        if (idx < N_) {
            rowptr[idx] = run;
            cursor[idx] = run;
            run += deg[idx];
        }
    }
    if (t == 1023) rowptr[N_] = part[1023];
}

__global__ void scatter_kernel(const int* __restrict__ dst, int* __restrict__ cursor,
                               int* __restrict__ eidx, int E_) {
    int e = blockIdx.x * 256 + threadIdx.x;
    if (e >= E_) return;
    int pos = atomicAdd(&cursor[dst[e]], 1);
    eidx[pos] = e;
}

// ---------------------------------------------------------------------------
// attn_fused: 1 wave/node, 4 edges in flight (16-lane groups), eidx gather.
// Scores in log2 units (folded into Mcat).
// ---------------------------------------------------------------------------
__global__ __launch_bounds__(256) void attn_fused(
    const unsigned short* __restrict__ qkt, const unsigned short* __restrict__ h,
    const int* __restrict__ rowptr, const int* __restrict__ eidx,
    unsigned short* __restrict__ whm, int N_)
{
    const int n = blockIdx.x * 4 + (threadIdx.x >> 6);
    if (n >= N_) return;
    const int lane = threadIdx.x & 63;
    const int g = lane >> 4, s = lane & 15;

    const int beg = rowptr[n], end = rowptr[n + 1];
    unsigned short* outp = whm + (size_t)n * 512 + g * 128 + s * 8;
    if (beg == end) {
        *reinterpret_cast<uint2*>(outp) = make_uint2(0u, 0u);
        *reinterpret_cast<uint2*>(outp + 4) = make_uint2(0u, 0u);
        return;
    }

    float qk[4][8];
#pragma unroll
    for (int hd = 0; hd < 4; hd++) {
        uint4 u = *reinterpret_cast<const uint4*>(qkt + (size_t)n * 512 + hd * 128 + s * 8);
        qk[hd][0] = bf2f((unsigned short)(u.x & 0xffff)); qk[hd][1] = bf2f((unsigned short)(u.x >> 16));
        qk[hd][2] = bf2f((unsigned short)(u.y & 0xffff)); qk[hd][3] = bf2f((unsigned short)(u.y >> 16));
        qk[hd][4] = bf2f((unsigned short)(u.z & 0xffff)); qk[hd][5] = bf2f((unsigned short)(u.z >> 16));
        qk[hd][6] = bf2f((unsigned short)(u.w & 0xffff)); qk[hd][7] = bf2f((unsigned short)(u.w >> 16));
    }

    float m[4], l[4], a[4][8];
#pragma unroll
    for (int hd = 0; hd < 4; hd++) {
        m[hd] = -3.0e38f; l[hd] = 0.f;
#pragma unroll
        for (int j = 0; j < 8; j++) a[hd][j] = 0.f;
    }

    const int T = (end - beg + 3) >> 2;
    int idx = beg + g;
    uint4 hv = make_uint4(0u, 0u, 0u, 0u);
    if (idx < end) hv = *reinterpret_cast<const uint4*>(h + (size_t)eidx[idx] * 128 + s * 8);

    for (int it = 0; it < T; it++) {
        const uint4 hc = hv;
        const bool valid = (idx < end);
        const int nidx = idx + 4;
        if (nidx < end) hv = *reinterpret_cast<const uint4*>(h + (size_t)eidx[nidx] * 128 + s * 8);
        idx = nidx;

        float hf[8];
        hf[0] = bf2f((unsigned short)(hc.x & 0xffff)); hf[1] = bf2f((unsigned short)(hc.x >> 16));
        hf[2] = bf2f((unsigned short)(hc.y & 0xffff)); hf[3] = bf2f((unsigned short)(hc.y >> 16));
        hf[4] = bf2f((unsigned short)(hc.z & 0xffff)); hf[5] = bf2f((unsigned short)(hc.z >> 16));
        hf[6] = bf2f((unsigned short)(hc.w & 0xffff)); hf[7] = bf2f((unsigned short)(hc.w >> 16));

        float part[4];
#pragma unroll
        for (int hd = 0; hd < 4; hd++) {
            float pp = 0.f;
#pragma unroll
            for (int j = 0; j < 8; j++) pp += qk[hd][j] * hf[j];
            part[hd] = pp;
        }
#pragma unroll
        for (int off = 1; off < 16; off <<= 1) {
#pragma unroll
            for (int hd = 0; hd < 4; hd++)
                part[hd] += __shfl_xor(part[hd], off, 64);
        }

        if (valid) {
#pragma unroll
            for (int hd = 0; hd < 4; hd++) {
                const float sv = part[hd];
                const float mn = fmaxf(m[hd], sv);
                const float sc = EXP2(m[hd] - mn);
                const float pp = EXP2(sv - mn);
                l[hd] = l[hd] * sc + pp;
#pragma unroll
                for (int j = 0; j < 8; j++) a[hd][j] = a[hd][j] * sc + pp * hf[j];
                m[hd] = mn;
            }
        }
    }

#pragma unroll
    for (int off = 16; off <= 32; off <<= 1) {
#pragma unroll
        for (int hd = 0; hd < 4; hd++) {
            const float mo = __shfl_xor(m[hd], off, 64);
            const float lo = __shfl_xor(l[hd], off, 64);
            const float mn = fmaxf(m[hd], mo);
            const float sc = EXP2(m[hd] - mn);
            const float so = EXP2(mo - mn);
            l[hd] = l[hd] * sc + lo * so;
#pragma unroll
            for (int j = 0; j < 8; j++) {
                const float ao = __shfl_xor(a[hd][j], off, 64);
                a[hd][j] = a[hd][j] * sc + ao * so;
            }
            m[hd] = mn;
        }
    }

#pragma unroll
    for (int hd = 0; hd < 4; hd++) {
        if (g == hd) {
            const float rl = 1.f / l[hd];
            uint4 o;
            o.x = pack2(a[hd][0] * rl, a[hd][1] * rl);
            o.y = pack2(a[hd][2] * rl, a[hd][3] * rl);
            o.z = pack2(a[hd][4] * rl, a[hd][5] * rl);
            o.w = pack2(a[hd][6] * rl, a[hd][7] * rl);
            *reinterpret_cast<uint4*>(outp) = o;
        }
    }
}

// mail[n] = sum over incoming edges of h[e]; 4-edge-group eidx gather.
__global__ __launch_bounds__(256) void mail_csr(
    const unsigned short* __restrict__ h,
    const int* __restrict__ rowptr, const int* __restrict__ eidx,
    unsigned short* __restrict__ mailb, int N_)
{
    const int n = blockIdx.x * 4 + (threadIdx.x >> 6);
    if (n >= N_) return;
    const int lane = threadIdx.x & 63;
    const int g = lane >> 4, s = lane & 15;

    const int beg = rowptr[n], end = rowptr[n + 1];

    float a[8];
#pragma unroll
    for (int j = 0; j < 8; j++) a[j] = 0.f;

    const int T = (end - beg + 3) >> 2;
    int idx = beg + g;
    uint4 hv = make_uint4(0u, 0u, 0u, 0u);
    if (idx < end) hv = *reinterpret_cast<const uint4*>(h + (size_t)eidx[idx] * 128 + s * 8);

    for (int it = 0; it < T; it++) {
        const uint4 hc = hv;
        const bool valid = (idx < end);
        const int nidx = idx + 4;
        if (nidx < end) hv = *reinterpret_cast<const uint4*>(h + (size_t)eidx[nidx] * 128 + s * 8);
        idx = nidx;
        if (valid) {
            a[0] += bf2f((unsigned short)(hc.x & 0xffff)); a[1] += bf2f((unsigned short)(hc.x >> 16));
            a[2] += bf2f((unsigned short)(hc.y & 0xffff)); a[3] += bf2f((unsigned short)(hc.y >> 16));
            a[4] += bf2f((unsigned short)(hc.z & 0xffff)); a[5] += bf2f((unsigned short)(hc.z >> 16));
            a[6] += bf2f((unsigned short)(hc.w & 0xffff)); a[7] += bf2f((unsigned short)(hc.w >> 16));
        }
    }
#pragma unroll
    for (int off = 16; off <= 32; off <<= 1)
#pragma unroll
        for (int j = 0; j < 8; j++) a[j] += __shfl_xor(a[j], off, 64);

    if (g == 0) {
        uint4 o;
        o.x = pack2(a[0], a[1]); o.y = pack2(a[2], a[3]);
        o.z = pack2(a[4], a[5]); o.w = pack2(a[6], a[7]);
        *reinterpret_cast<uint4*>(mailb + (size_t)n * 128 + s * 8) = o;
    }
}

// ---------------------------------------------------------------------------
// Precompute kernels
// ---------------------------------------------------------------------------
struct W5 { const float* p[5]; };

__global__ void cvt_wT(W5 w, unsigned short* __restrict__ out) {
    const float* src = w.p[blockIdx.x];
    unsigned short* dst = out + (size_t)blockIdx.x * 16384;
    for (int idx = threadIdx.x; idx < 16384; idx += 256) {
        const int k = idx >> 7, n = idx & 127;
        dst[n * 128 + k] = f2bf(src[idx]);
    }
}

// Score scale folded into Mcat: 1/sqrt(32) * log2(e), so attn uses exp2.
#define SCORE_SCALE 0.25508994161f

__global__ void mcat_kernel(const float* __restrict__ Wq, const float* __restrict__ Wk,
                            const float* __restrict__ bq,
                            unsigned short* __restrict__ McatT, float* __restrict__ cbias) {
    const int oc = blockIdx.x;            // 0..511
    const int hd = oc >> 7, ip = oc & 127;
    const int a = threadIdx.x;            // 0..127
    const float* wk = Wk + ip * 128 + hd * 32;
    const float* wq = Wq + a * 128 + hd * 32;
    float s = 0.f;
    for (int jj = 0; jj < 32; jj++) s += wq[jj] * wk[jj];
    McatT[(size_t)oc * 128 + a] = f2bf(s * SCORE_SCALE);
    if (a == 0) {
        float c = 0.f;
        for (int jj = 0; jj < 32; jj++) c += bq[hd * 32 + jj] * wk[jj];
        cbias[oc] = c * SCORE_SCALE;
    }
}

__global__ void pcat_kernel(const float* __restrict__ Wv, const float* __restrict__ Wo,
                            unsigned short* __restrict__ PcatT) {
    const int j = blockIdx.x;             // 0..127
    const int k = threadIdx.x;            // 0..511
    const int hd = k >> 7, i = k & 127;
    float s = 0.f;
    for (int cc = 0; cc < 32; cc++)
        s += Wv[i * 128 + hd * 32 + cc] * Wo[(hd * 32 + cc) * 128 + j];
    PcatT[(size_t)j * 512 + k] = f2bf(s);
}

__global__ void bias2_kernel(const float* __restrict__ bv, const float* __restrict__ Wo,
                             const float* __restrict__ bo, float* __restrict__ bias2) {
    const int j = threadIdx.x;
    if (j >= 128) return;
    float s = 0.f;
    for (int c = 0; c < 128; c++) s += bv[c] * Wo[c * 128 + j];
    bias2[j] = s + bo[j];
}

__global__ void cvt_bf16(const float* __restrict__ in, unsigned short* __restrict__ out, long n4) {
    long i = (long)blockIdx.x * 256 + threadIdx.x;
    if (i >= n4) return;
    float4 v = reinterpret_cast<const float4*>(in)[i];
    ushort4 o;
    o.x = f2bf(v.x); o.y = f2bf(v.y); o.z = f2bf(v.z); o.w = f2bf(v.w);
    reinterpret_cast<ushort4*>(out)[i] = o;
}

__global__ void prep_f(const float* __restrict__ f, unsigned short* __restrict__ fb,
                       float* __restrict__ f_h, int n4) {
    int i = blockIdx.x * 256 + threadIdx.x;
    if (i >= n4) return;
    float4 v = reinterpret_cast<const float4*>(f)[i];
    reinterpret_cast<float4*>(f_h)[i] = v;
    ushort4 o;
    o.x = f2bf(v.x); o.y = f2bf(v.y); o.z = f2bf(v.z); o.w = f2bf(v.w);
    reinterpret_cast<ushort4*>(fb)[i] = o;
}

// ---------------------------------------------------------------------------
extern "C" void kernel_launch(void* const* d_in, const int* in_sizes, int n_in,
                              void* d_out, int out_size, void* d_ws, size_t ws_size,
                              hipStream_t stream)
{
    const float* f      = (const float*)d_in[0];
    const float* x      = (const float*)d_in[1];
    const int*   src    = (const int*)d_in[2];
    const int*   dst    = (const int*)d_in[3];
    const float* Wq     = (const float*)d_in[4];
    const float* bq     = (const float*)d_in[5];
    const float* Wk     = (const float*)d_in[6];
    const float* bk     = (const float*)d_in[7];   // cancels in softmax
    const float* Wv     = (const float*)d_in[8];
    const float* bv     = (const float*)d_in[9];
    const float* Wo     = (const float*)d_in[10];
    const float* bo     = (const float*)d_in[11];
    const float* W_mp   = (const float*)d_in[12];
    const float* b_mp   = (const float*)d_in[13];
    const float* W_last = (const float*)d_in[14];
    const float* b_last = (const float*)d_in[15];
    (void)bk;

    const int N = in_sizes[0] / 128;
    const int E = in_sizes[1] / 128;

    char* p = (char*)d_ws;
    auto take = [&](size_t bytes) { char* r = p; p += (bytes + 255) & ~(size_t)255; return r; };
    unsigned short* w5T   = (unsigned short*)take(5 * 16384 * 2);
    unsigned short* McatT = (unsigned short*)take(512 * 128 * 2);
    unsigned short* PcatT = (unsigned short*)take(128 * 512 * 2);
    float* cbias  = (float*)take(512 * 4);
    float* bias2  = (float*)take(128 * 4);
    unsigned short* xb    = (unsigned short*)take((size_t)E * 128 * 2);
    unsigned short* h1    = (unsigned short*)take((size_t)E * 128 * 2);
    unsigned short* h2    = (unsigned short*)take((size_t)E * 128 * 2);
    unsigned short* fb    = (unsigned short*)take((size_t)N * 128 * 2);
    unsigned short* f_hb  = (unsigned short*)take((size_t)N * 128 * 2);
    unsigned short* qkt   = (unsigned short*)take((size_t)N * 512 * 2);
    unsigned short* whm   = (unsigned short*)take((size_t)N * 512 * 2);
    unsigned short* mailb = (unsigned short*)take((size_t)N * 128 * 2);
    float* f_h    = (float*)take((size_t)N * 128 * 4);
    int* deg      = (int*)take((size_t)N * 4);
    int* rowptr   = (int*)take((size_t)(N + 1) * 4);
    int* cursor   = (int*)take((size_t)N * 4);
    int* eidx     = (int*)take((size_t)E * 4);

    const unsigned short* Wm0T = w5T + 0 * 16384;
    const unsigned short* Wm1T = w5T + 1 * 16384;
    const unsigned short* WL0T = w5T + 2 * 16384;
    const unsigned short* WL1T = w5T + 3 * 16384;
    const unsigned short* WL2T = w5T + 4 * 16384;

    W5 w5;
    w5.p[0] = W_mp; w5.p[1] = W_mp + 16384;
    w5.p[2] = W_last; w5.p[3] = W_last + 16384; w5.p[4] = W_last + 32768;

    // --- setup: weights, folded matrices, bf16 copies, CSR ---
    cvt_wT<<<5, 256, 0, stream>>>(w5, w5T);
    mcat_kernel<<<512, 128, 0, stream>>>(Wq, Wk, bq, McatT, cbias);
    pcat_kernel<<<128, 512, 0, stream>>>(Wv, Wo, PcatT);
    bias2_kernel<<<1, 128, 0, stream>>>(bv, Wo, bo, bias2);
    cvt_bf16<<<(int)(((long)E * 32 + 255) / 256), 256, 0, stream>>>(x, xb, (long)E * 32);
    prep_f<<<(N * 32 + 255) / 256, 256, 0, stream>>>(f, fb, f_h, N * 32);

    hipMemsetAsync(deg, 0, (size_t)N * 4, stream);
    hist_kernel<<<(E + 255) / 256, 256, 0, stream>>>(dst, deg, E);
    scan_kernel<<<1, 1024, 0, stream>>>(deg, rowptr, cursor, N);
    scatter_kernel<<<(E + 255) / 256, 256, 0, stream>>>(dst, cursor, eidx, E);

    const int ntN = (N + 63) / 64;
    const int ntE = (E + 63) / 64;
    const int gNode = (N + 3) / 4;
    const int gMrelu = (ntE < 1280) ? ntE : 1280;   // 5 blocks/CU

    const unsigned short* hc = xb;
    unsigned short* houts[2] = { h1, h2 };
    for (int it = 0; it < 2; it++) {
        const unsigned short* fh_in = (it == 0) ? fb : f_hb;
        // qkt = f_h @ Mcat + c   (bf16 [N,512], log2-scaled scores)
        gemm_q512<<<ntN, 512, 0, stream>>>(fh_in, McatT, cbias, qkt, N);
        // fused attention -> normalized weighted mailbox whm (bf16 [N,512])
        attn_fused<<<gNode, 256, 0, stream>>>(qkt, hc, rowptr, eidx, whm, N);
        // f_h += whm @ Pcat + bias2 ; f_hb = bf16(f_h)
        gemm_k512<<<ntN, 256, 0, stream>>>(whm, PcatT, bias2, f_h, f_hb, N);
        // h' = relu(x + (f_hb[src] - rev(h)) @ Wm + b)
        gemm_mrelu<<<gMrelu, 256, 0, stream>>>(
            f_hb, hc, src, (it == 0) ? Wm0T : Wm1T, b_mp + (size_t)it * 128,
            xb, houts[it], E, ntE);
        hc = houts[it];
    }

    // mail = segment_sum(h, dst)
    mail_csr<<<gNode, 256, 0, stream>>>(hc, rowptr, eidx, mailb, N);

    // out = [mail | f_h | f] @ [WL0;WL1;WL2] + b_last  (one fused GEMM)
    gemm_final<<<ntN, 256, 0, stream>>>(
        mailb, f_hb, fb, WL0T, WL1T, WL2T, b_last, (float*)d_out, N);
}

// Round 9
// 554.784 us; speedup vs baseline: 1.3600x; 1.3600x over previous
//
#include <hip/hip_runtime.h>
#include <hip/hip_bf16.h>

typedef __attribute__((ext_vector_type(8))) short bf16x8;
typedef __attribute__((ext_vector_type(4))) float f32x4;

__device__ __forceinline__ unsigned short f2bf(float f) {
    unsigned u = __float_as_uint(f);
    unsigned r = (u + 0x7FFFu + ((u >> 16) & 1u)) >> 16;  // RNE
    return (unsigned short)r;
}
__device__ __forceinline__ float bf2f(unsigned short b) {
    return __uint_as_float(((unsigned)b) << 16);
}
__device__ __forceinline__ unsigned pack2(float a, float b) {
    return (unsigned)f2bf(a) | ((unsigned)f2bf(b) << 16);
}
__device__ __forceinline__ unsigned pksub(unsigned a, unsigned b) {
    float r0 = bf2f((unsigned short)(a & 0xffff)) - bf2f((unsigned short)(b & 0xffff));
    float r1 = bf2f((unsigned short)(a >> 16))    - bf2f((unsigned short)(b >> 16));
    return pack2(r0, r1);
}
#define EXP2(x) __builtin_amdgcn_exp2f(x)

__device__ __forceinline__ void gload_lds16(const void* g, void* l) {
    __builtin_amdgcn_global_load_lds(
        (const __attribute__((address_space(1))) unsigned int*)g,
        (__attribute__((address_space(3))) unsigned int*)l,
        16, 0, 0);
}

// ---------------------------------------------------------------------------
// gemm_q512: qkt[M x 512](bf16) = A[M x 128](bf16) @ McatT + cbias.
// ---------------------------------------------------------------------------
__global__ __launch_bounds__(512, 2) void gemm_q512(
    const unsigned short* __restrict__ A, const unsigned short* __restrict__ WT,
    const float* __restrict__ bias, unsigned short* __restrict__ out, int M)
{
    __shared__ __align__(16) unsigned short As[64 * 128];

    const int t = threadIdx.x, wave = t >> 6, lane = t & 63;
    const int lr = lane & 15, lk = lane >> 4;

    bf16x8 Bf[4][4];
    f32x4 bs[4];
#pragma unroll
    for (int fn = 0; fn < 4; fn++) {
        const int col0 = wave * 64 + fn * 16 + lk * 4;
        bs[fn] = *reinterpret_cast<const f32x4*>(bias + col0);
        const int n = wave * 64 + fn * 16 + lr;
#pragma unroll
        for (int kk = 0; kk < 4; kk++)
            Bf[kk][fn] = *reinterpret_cast<const bf16x8*>(WT + n * 128 + kk * 32 + lk * 8);
    }

    const int row0 = blockIdx.x * 64;
#pragma unroll
    for (int i = 0; i < 2; i++) {
        const int flat = (i * 512 + t) * 16;
        const int r = flat >> 8, c = (flat >> 4) & 15;
        int gr = row0 + r; if (gr >= M) gr = M - 1;
        const void* g = A + (size_t)gr * 128 + ((c ^ (r & 7)) << 3);
        void* l = (void*)((char*)&As[0] + (size_t)(i * 512 + wave * 64) * 16 + 0);
        gload_lds16(g, l);
    }
    __syncthreads();

    f32x4 acc[4][4];
#pragma unroll
    for (int a = 0; a < 4; a++)
#pragma unroll
        for (int b = 0; b < 4; b++) acc[a][b] = (f32x4){0.f, 0.f, 0.f, 0.f};

#pragma unroll
    for (int kk = 0; kk < 4; kk++) {
        bf16x8 af[4];
#pragma unroll
        for (int fm = 0; fm < 4; fm++) {
            const int r = fm * 16 + lr;
            const int c = (kk * 4 + lk) ^ (r & 7);
            af[fm] = *reinterpret_cast<const bf16x8*>(&As[r * 128 + c * 8]);
        }
#pragma unroll
        for (int fm = 0; fm < 4; fm++)
#pragma unroll
            for (int fn = 0; fn < 4; fn++)
                acc[fm][fn] = __builtin_amdgcn_mfma_f32_16x16x32_bf16(
                    Bf[kk][fn], af[fm], acc[fm][fn], 0, 0, 0);
    }

#pragma unroll
    for (int fm = 0; fm < 4; fm++) {
        const int row = row0 + fm * 16 + lr;
        if (row < M) {
#pragma unroll
            for (int fn = 0; fn < 4; fn++) {
                const int col0 = wave * 64 + fn * 16 + lk * 4;
                f32x4 vv = acc[fm][fn] + bs[fn];
                uint2 o; o.x = pack2(vv[0], vv[1]); o.y = pack2(vv[2], vv[3]);
                *reinterpret_cast<uint2*>(out + (size_t)row * 512 + col0) = o;
            }
        }
    }
}

// ---------------------------------------------------------------------------
// gemm_k512: f_h[M x 128](fp32) += A[M x 512](bf16) @ PcatT + bias2;
// also emits f_hb bf16.
// ---------------------------------------------------------------------------
__global__ __launch_bounds__(256, 2) void gemm_k512(
    const unsigned short* __restrict__ A, const unsigned short* __restrict__ WT,
    const float* __restrict__ bias, float* __restrict__ f_h,
    unsigned short* __restrict__ f_hb, int M)
{
    __shared__ __align__(16) unsigned short As[64 * 512];  // 64KB

    const int t = threadIdx.x, wave = t >> 6, lane = t & 63;
    const int lr = lane & 15, lk = lane >> 4;

    bf16x8 Bf[16][2];
    f32x4 bs[2];
#pragma unroll
    for (int fn = 0; fn < 2; fn++) {
        const int col0 = wave * 32 + fn * 16 + lk * 4;
        bs[fn] = *reinterpret_cast<const f32x4*>(bias + col0);
        const int n = wave * 32 + fn * 16 + lr;
#pragma unroll
        for (int kk = 0; kk < 16; kk++)
            Bf[kk][fn] = *reinterpret_cast<const bf16x8*>(WT + n * 512 + kk * 32 + lk * 8);
    }

    const int row0 = blockIdx.x * 64;
#pragma unroll
    for (int i = 0; i < 16; i++) {
        const int flat = (i * 256 + t) * 16;
        const int r = flat >> 10, c = (flat >> 4) & 63;
        int gr = row0 + r; if (gr >= M) gr = M - 1;
        const void* g = A + (size_t)gr * 512 + ((c ^ (r & 7)) << 3);
        void* l = (void*)((char*)&As[0] + (size_t)(i * 256 + wave * 64) * 16);
        gload_lds16(g, l);
    }
    __syncthreads();

    f32x4 acc[4][2];
#pragma unroll
    for (int a = 0; a < 4; a++)
#pragma unroll
        for (int b = 0; b < 2; b++) acc[a][b] = (f32x4){0.f, 0.f, 0.f, 0.f};

#pragma unroll
    for (int kk = 0; kk < 16; kk++) {
        bf16x8 af[4];
#pragma unroll
        for (int fm = 0; fm < 4; fm++) {
            const int r = fm * 16 + lr;
            const int c = (kk * 4 + lk) ^ (r & 7);
            af[fm] = *reinterpret_cast<const bf16x8*>(&As[r * 512 + c * 8]);
        }
#pragma unroll
        for (int fm = 0; fm < 4; fm++)
#pragma unroll
            for (int fn = 0; fn < 2; fn++)
                acc[fm][fn] = __builtin_amdgcn_mfma_f32_16x16x32_bf16(
                    Bf[kk][fn], af[fm], acc[fm][fn], 0, 0, 0);
    }

#pragma unroll
    for (int fm = 0; fm < 4; fm++) {
        const int row = row0 + fm * 16 + lr;
        if (row < M) {
#pragma unroll
            for (int fn = 0; fn < 2; fn++) {
                const int col0 = wave * 32 + fn * 16 + lk * 4;
                const size_t off = (size_t)row * 128 + col0;
                f32x4 vv = acc[fm][fn] + bs[fn];
                vv += *reinterpret_cast<const f32x4*>(f_h + off);
                *reinterpret_cast<f32x4*>(f_h + off) = vv;
                uint2 o; o.x = pack2(vv[0], vv[1]); o.y = pack2(vv[2], vv[3]);
                *reinterpret_cast<uint2*>(f_hb + off) = o;
            }
        }
    }
}

// ---------------------------------------------------------------------------
// gemm_mrelu: h' = relu(x + (f_hb[src[e]] - h[e^1]) @ Wm + b). Reg-staged.
// launch_bounds(256,3): VGPR 76, no spill (ERRATA: (256,5) forced 48 VGPR
// -> scratch spill, FETCH +120MB, 1.6x slower). Grid 1280 -> up to 5 blk/CU.
// ---------------------------------------------------------------------------
__global__ __launch_bounds__(256, 3) void gemm_mrelu(
    const unsigned short* __restrict__ f_hb, const unsigned short* __restrict__ h,
    const int* __restrict__ src, const unsigned short* __restrict__ WT,
    const float* __restrict__ bias, const unsigned short* __restrict__ resx,
    unsigned short* __restrict__ out, int E, int ntiles)
{
    __shared__ __align__(16) unsigned short As[2][64 * 128];

    const int t = threadIdx.x, wave = t >> 6, lane = t & 63;
    const int lr = lane & 15, lk = lane >> 4;

    bf16x8 Bf[4][2];
    f32x4 bs[2];
#pragma unroll
    for (int fn = 0; fn < 2; fn++) {
        const int col0 = wave * 32 + fn * 16 + lk * 4;
        bs[fn] = *reinterpret_cast<const f32x4*>(bias + col0);
        const int n = wave * 32 + fn * 16 + lr;
#pragma unroll
        for (int kk = 0; kk < 4; kk++)
            Bf[kk][fn] = *reinterpret_cast<const bf16x8*>(WT + n * 128 + kk * 32 + lk * 8);
    }

    uint4 Lh[4], Lf[4];
    auto load_t = [&](int row0) {
#pragma unroll
        for (int i = 0; i < 4; i++) {
            const int flat = (wave * 4 + i) * 1024 + lane * 16;
            const int r = flat >> 8, c = (flat >> 4) & 15;
            int e = row0 + r; if (e >= E) e = E - 1;
            Lh[i] = *reinterpret_cast<const uint4*>(h + (size_t)(e ^ 1) * 128 + c * 8);
            const int se = src[e];
            Lf[i] = *reinterpret_cast<const uint4*>(f_hb + (size_t)se * 128 + c * 8);
        }
    };
    auto write_t = [&](int buf) {
#pragma unroll
        for (int i = 0; i < 4; i++) {
            const int flat = (wave * 4 + i) * 1024 + lane * 16;
            const int r = flat >> 8, c = (flat >> 4) & 15;
            uint4 d;
            d.x = pksub(Lf[i].x, Lh[i].x); d.y = pksub(Lf[i].y, Lh[i].y);
            d.z = pksub(Lf[i].z, Lh[i].z); d.w = pksub(Lf[i].w, Lh[i].w);
            *reinterpret_cast<uint4*>(&As[buf][r * 128 + ((c ^ (r & 7)) << 3)]) = d;
        }
    };

    int tt = blockIdx.x;
    if (tt >= ntiles) return;
    load_t(tt * 64);
    write_t(0);
    int cur = 0;
    __syncthreads();

    for (; tt < ntiles; tt += gridDim.x) {
        const int nxt = tt + gridDim.x;
        if (nxt < ntiles) load_t(nxt * 64);

        f32x4 acc[4][2];
#pragma unroll
        for (int a = 0; a < 4; a++)
#pragma unroll
            for (int b = 0; b < 2; b++) acc[a][b] = (f32x4){0.f, 0.f, 0.f, 0.f};

#pragma unroll
        for (int kk = 0; kk < 4; kk++) {
            bf16x8 af[4];
#pragma unroll
            for (int fm = 0; fm < 4; fm++) {
                const int r = fm * 16 + lr;
                const int c = (kk * 4 + lk) ^ (r & 7);
                af[fm] = *reinterpret_cast<const bf16x8*>(&As[cur][r * 128 + c * 8]);
            }
#pragma unroll
            for (int fm = 0; fm < 4; fm++)
#pragma unroll
                for (int fn = 0; fn < 2; fn++)
                    acc[fm][fn] = __builtin_amdgcn_mfma_f32_16x16x32_bf16(
                        Bf[kk][fn], af[fm], acc[fm][fn], 0, 0, 0);
        }

        const int row0 = tt * 64;
#pragma unroll
        for (int fm = 0; fm < 4; fm++) {
            const int row = row0 + fm * 16 + lr;
            if (row < E) {
#pragma unroll
                for (int fn = 0; fn < 2; fn++) {
                    const int col0 = wave * 32 + fn * 16 + lk * 4;
                    const size_t off = (size_t)row * 128 + col0;
                    f32x4 vv = acc[fm][fn] + bs[fn];
                    uint2 rb = *reinterpret_cast<const uint2*>(resx + off);
                    vv[0] += bf2f((unsigned short)(rb.x & 0xffff));
                    vv[1] += bf2f((unsigned short)(rb.x >> 16));
                    vv[2] += bf2f((unsigned short)(rb.y & 0xffff));
                    vv[3] += bf2f((unsigned short)(rb.y >> 16));
                    vv[0] = fmaxf(vv[0], 0.f); vv[1] = fmaxf(vv[1], 0.f);
                    vv[2] = fmaxf(vv[2], 0.f); vv[3] = fmaxf(vv[3], 0.f);
                    uint2 o; o.x = pack2(vv[0], vv[1]); o.y = pack2(vv[2], vv[3]);
                    *reinterpret_cast<uint2*>(out + off) = o;
                }
            }
        }

        if (nxt < ntiles) write_t(cur ^ 1);
        __syncthreads();
        cur ^= 1;
    }
}

// ---------------------------------------------------------------------------
// gemm_final: out[M x 128](fp32) = [A0|A1|A2] @ [W0;W1;W2] + bias. One shot.
// ---------------------------------------------------------------------------
__global__ __launch_bounds__(256, 2) void gemm_final(
    const unsigned short* __restrict__ A0, const unsigned short* __restrict__ A1,
    const unsigned short* __restrict__ A2,
    const unsigned short* __restrict__ W0T, const unsigned short* __restrict__ W1T,
    const unsigned short* __restrict__ W2T,
    const float* __restrict__ bias, float* __restrict__ out, int M)
{
    __shared__ __align__(16) unsigned short As[3][64 * 128];  // 48KB

    const int t = threadIdx.x, wave = t >> 6, lane = t & 63;
    const int lr = lane & 15, lk = lane >> 4;

    const unsigned short* Asrc[3] = { A0, A1, A2 };
    const unsigned short* Wsrc[3] = { W0T, W1T, W2T };

    bf16x8 Bf[12][2];
    f32x4 bs[2];
#pragma unroll
    for (int fn = 0; fn < 2; fn++) {
        const int col0 = wave * 32 + fn * 16 + lk * 4;
        bs[fn] = *reinterpret_cast<const f32x4*>(bias + col0);
        const int n = wave * 32 + fn * 16 + lr;
#pragma unroll
        for (int b = 0; b < 3; b++)
#pragma unroll
            for (int kk = 0; kk < 4; kk++)
                Bf[b * 4 + kk][fn] = *reinterpret_cast<const bf16x8*>(
                    Wsrc[b] + n * 128 + kk * 32 + lk * 8);
    }

    const int row0 = blockIdx.x * 64;
#pragma unroll
    for (int b = 0; b < 3; b++) {
#pragma unroll
        for (int i = 0; i < 4; i++) {
            const int flat = (wave * 4 + i) * 1024 + lane * 16;
            const int r = flat >> 8, c = (flat >> 4) & 15;
            int gr = row0 + r; if (gr >= M) gr = M - 1;
            const void* g = Asrc[b] + (size_t)gr * 128 + ((c ^ (r & 7)) << 3);
            void* l = (void*)((char*)&As[b][0] + (size_t)(wave * 4 + i) * 1024);
            gload_lds16(g, l);
        }
    }
    __syncthreads();

    f32x4 acc[4][2];
#pragma unroll
    for (int a = 0; a < 4; a++)
#pragma unroll
        for (int b = 0; b < 2; b++) acc[a][b] = (f32x4){0.f, 0.f, 0.f, 0.f};

#pragma unroll
    for (int b = 0; b < 3; b++) {
#pragma unroll
        for (int kk = 0; kk < 4; kk++) {
            bf16x8 af[4];
#pragma unroll
            for (int fm = 0; fm < 4; fm++) {
                const int r = fm * 16 + lr;
                const int c = (kk * 4 + lk) ^ (r & 7);
                af[fm] = *reinterpret_cast<const bf16x8*>(&As[b][r * 128 + c * 8]);
            }
#pragma unroll
            for (int fm = 0; fm < 4; fm++)
#pragma unroll
                for (int fn = 0; fn < 2; fn++)
                    acc[fm][fn] = __builtin_amdgcn_mfma_f32_16x16x32_bf16(
                        Bf[b * 4 + kk][fn], af[fm], acc[fm][fn], 0, 0, 0);
        }
    }

#pragma unroll
    for (int fm = 0; fm < 4; fm++) {
        const int row = row0 + fm * 16 + lr;
        if (row < M) {
#pragma unroll
            for (int fn = 0; fn < 2; fn++) {
                const int col0 = wave * 32 + fn * 16 + lk * 4;
                *reinterpret_cast<f32x4*>(out + (size_t)row * 128 + col0) =
                    acc[fm][fn] + bs[fn];
            }
        }
    }
}

// ---------------------------------------------------------------------------
// CSR build
// ---------------------------------------------------------------------------
__global__ void hist_kernel(const int* __restrict__ dst, int* __restrict__ deg, int E_) {
    int e = blockIdx.x * 256 + threadIdx.x;
    if (e < E_) atomicAdd(&deg[dst[e]], 1);
}

__global__ __launch_bounds__(1024) void scan_kernel(
    const int* __restrict__ deg, int* __restrict__ rowptr,
    int* __restrict__ cursor, int N_)
{
    __shared__ int part[1024];
    const int t = threadIdx.x;
    const int chunk = (N_ + 1023) >> 10;
    const int base = t * chunk;
    int s = 0;
    for (int i = 0; i < chunk; i++) {
        int idx = base + i;
        if (idx < N_) s += deg[idx];
    }
    part[t] = s;
    __syncthreads();
    for (int off = 1; off < 1024; off <<= 1) {
        int v = (t >= off) ? part[t - off] : 0;
        __syncthreads();
        part[t] += v;
        __syncthreads();
    }
    int run = (t == 0) ? 0 : part[t - 1];
    for (int i = 0; i < chunk; i++) {
        int idx = base + i;
        if (idx < N_) {
            rowptr[idx] = run;
            cursor[idx] = run;
            run += deg[idx];
        }
    }
    if (t == 1023) rowptr[N_] = part[1023];
}

__global__ void scatter_kernel(const int* __restrict__ dst, int* __restrict__ cursor,
                               int* __restrict__ eidx, int E_) {
    int e = blockIdx.x * 256 + threadIdx.x;
    if (e >= E_) return;
    int pos = atomicAdd(&cursor[dst[e]], 1);
    eidx[pos] = e;
}

// ---------------------------------------------------------------------------
// attn_fused: 1 wave/node, 4 edges in flight (16-lane groups), eidx gather.
// Scores in log2 units (folded into Mcat).
// ---------------------------------------------------------------------------
__global__ __launch_bounds__(256) void attn_fused(
    const unsigned short* __restrict__ qkt, const unsigned short* __restrict__ h,
    const int* __restrict__ rowptr, const int* __restrict__ eidx,
    unsigned short* __restrict__ whm, int N_)
{
    const int n = blockIdx.x * 4 + (threadIdx.x >> 6);
    if (n >= N_) return;
    const int lane = threadIdx.x & 63;
    const int g = lane >> 4, s = lane & 15;

    const int beg = rowptr[n], end = rowptr[n + 1];
    unsigned short* outp = whm + (size_t)n * 512 + g * 128 + s * 8;
    if (beg == end) {
        *reinterpret_cast<uint2*>(outp) = make_uint2(0u, 0u);
        *reinterpret_cast<uint2*>(outp + 4) = make_uint2(0u, 0u);
        return;
    }

    float qk[4][8];
#pragma unroll
    for (int hd = 0; hd < 4; hd++) {
        uint4 u = *reinterpret_cast<const uint4*>(qkt + (size_t)n * 512 + hd * 128 + s * 8);
        qk[hd][0] = bf2f((unsigned short)(u.x & 0xffff)); qk[hd][1] = bf2f((unsigned short)(u.x >> 16));
        qk[hd][2] = bf2f((unsigned short)(u.y & 0xffff)); qk[hd][3] = bf2f((unsigned short)(u.y >> 16));
        qk[hd][4] = bf2f((unsigned short)(u.z & 0xffff)); qk[hd][5] = bf2f((unsigned short)(u.z >> 16));
        qk[hd][6] = bf2f((unsigned short)(u.w & 0xffff)); qk[hd][7] = bf2f((unsigned short)(u.w >> 16));
    }

    float m[4], l[4], a[4][8];
#pragma unroll
    for (int hd = 0; hd < 4; hd++) {
        m[hd] = -3.0e38f; l[hd] = 0.f;
#pragma unroll
        for (int j = 0; j < 8; j++) a[hd][j] = 0.f;
    }

    const int T = (end - beg + 3) >> 2;
    int idx = beg + g;
    uint4 hv = make_uint4(0u, 0u, 0u, 0u);
    if (idx < end) hv = *reinterpret_cast<const uint4*>(h + (size_t)eidx[idx] * 128 + s * 8);

    for (int it = 0; it < T; it++) {
        const uint4 hc = hv;
        const bool valid = (idx < end);
        const int nidx = idx + 4;
        if (nidx < end) hv = *reinterpret_cast<const uint4*>(h + (size_t)eidx[nidx] * 128 + s * 8);
        idx = nidx;

        float hf[8];
        hf[0] = bf2f((unsigned short)(hc.x & 0xffff)); hf[1] = bf2f((unsigned short)(hc.x >> 16));
        hf[2] = bf2f((unsigned short)(hc.y & 0xffff)); hf[3] = bf2f((unsigned short)(hc.y >> 16));
        hf[4] = bf2f((unsigned short)(hc.z & 0xffff)); hf[5] = bf2f((unsigned short)(hc.z >> 16));
        hf[6] = bf2f((unsigned short)(hc.w & 0xffff)); hf[7] = bf2f((unsigned short)(hc.w >> 16));

        float part[4];
#pragma unroll
        for (int hd = 0; hd < 4; hd++) {
            float pp = 0.f;
#pragma unroll
            for (int j = 0; j < 8; j++) pp += qk[hd][j] * hf[j];
            part[hd] = pp;
        }
#pragma unroll
        for (int off = 1; off < 16; off <<= 1) {
#pragma unroll
            for (int hd = 0; hd < 4; hd++)
                part[hd] += __shfl_xor(part[hd], off, 64);
        }

        if (valid) {
#pragma unroll
            for (int hd = 0; hd < 4; hd++) {
                const float sv = part[hd];
                const float mn = fmaxf(m[hd], sv);
                const float sc = EXP2(m[hd] - mn);
                const float pp = EXP2(sv - mn);
                l[hd] = l[hd] * sc + pp;
#pragma unroll
                for (int j = 0; j < 8; j++) a[hd][j] = a[hd][j] * sc + pp * hf[j];
                m[hd] = mn;
            }
        }
    }

#pragma unroll
    for (int off = 16; off <= 32; off <<= 1) {
#pragma unroll
        for (int hd = 0; hd < 4; hd++) {
            const float mo = __shfl_xor(m[hd], off, 64);
            const float lo = __shfl_xor(l[hd], off, 64);
            const float mn = fmaxf(m[hd], mo);
            const float sc = EXP2(m[hd] - mn);
            const float so = EXP2(mo - mn);
            l[hd] = l[hd] * sc + lo * so;
#pragma unroll
            for (int j = 0; j < 8; j++) {
                const float ao = __shfl_xor(a[hd][j], off, 64);
                a[hd][j] = a[hd][j] * sc + ao * so;
            }
            m[hd] = mn;
        }
    }

#pragma unroll
    for (int hd = 0; hd < 4; hd++) {
        if (g == hd) {
            const float rl = 1.f / l[hd];
            uint4 o;
            o.x = pack2(a[hd][0] * rl, a[hd][1] * rl);
            o.y = pack2(a[hd][2] * rl, a[hd][3] * rl);
            o.z = pack2(a[hd][4] * rl, a[hd][5] * rl);
            o.w = pack2(a[hd][6] * rl, a[hd][7] * rl);
            *reinterpret_cast<uint4*>(outp) = o;
        }
    }
}

// mail[n] = sum over incoming edges of h[e]; 4-edge-group eidx gather.
__global__ __launch_bounds__(256) void mail_csr(
    const unsigned short* __restrict__ h,
    const int* __restrict__ rowptr, const int* __restrict__ eidx,
    unsigned short* __restrict__ mailb, int N_)
{
    const int n = blockIdx.x * 4 + (threadIdx.x >> 6);
    if (n >= N_) return;
    const int lane = threadIdx.x & 63;
    const int g = lane >> 4, s = lane & 15;

    const int beg = rowptr[n], end = rowptr[n + 1];

    float a[8];
#pragma unroll
    for (int j = 0; j < 8; j++) a[j] = 0.f;

    const int T = (end - beg + 3) >> 2;
    int idx = beg + g;
    uint4 hv = make_uint4(0u, 0u, 0u, 0u);
    if (idx < end) hv = *reinterpret_cast<const uint4*>(h + (size_t)eidx[idx] * 128 + s * 8);

    for (int it = 0; it < T; it++) {
        const uint4 hc = hv;
        const bool valid = (idx < end);
        const int nidx = idx + 4;
        if (nidx < end) hv = *reinterpret_cast<const uint4*>(h + (size_t)eidx[nidx] * 128 + s * 8);
        idx = nidx;
        if (valid) {
            a[0] += bf2f((unsigned short)(hc.x & 0xffff)); a[1] += bf2f((unsigned short)(hc.x >> 16));
            a[2] += bf2f((unsigned short)(hc.y & 0xffff)); a[3] += bf2f((unsigned short)(hc.y >> 16));
            a[4] += bf2f((unsigned short)(hc.z & 0xffff)); a[5] += bf2f((unsigned short)(hc.z >> 16));
            a[6] += bf2f((unsigned short)(hc.w & 0xffff)); a[7] += bf2f((unsigned short)(hc.w >> 16));
        }
    }
#pragma unroll
    for (int off = 16; off <= 32; off <<= 1)
#pragma unroll
        for (int j = 0; j < 8; j++) a[j] += __shfl_xor(a[j], off, 64);

    if (g == 0) {
        uint4 o;
        o.x = pack2(a[0], a[1]); o.y = pack2(a[2], a[3]);
        o.z = pack2(a[4], a[5]); o.w = pack2(a[6], a[7]);
        *reinterpret_cast<uint4*>(mailb + (size_t)n * 128 + s * 8) = o;
    }
}

// ---------------------------------------------------------------------------
// Precompute kernels
// ---------------------------------------------------------------------------
struct W5 { const float* p[5]; };

__global__ void cvt_wT(W5 w, unsigned short* __restrict__ out) {
    const float* src = w.p[blockIdx.x];
    unsigned short* dst = out + (size_t)blockIdx.x * 16384;
    for (int idx = threadIdx.x; idx < 16384; idx += 256) {
        const int k = idx >> 7, n = idx & 127;
        dst[n * 128 + k] = f2bf(src[idx]);
    }
}

// Score scale folded into Mcat: 1/sqrt(32) * log2(e), so attn uses exp2.
#define SCORE_SCALE 0.25508994161f

__global__ void mcat_kernel(const float* __restrict__ Wq, const float* __restrict__ Wk,
                            const float* __restrict__ bq,
                            unsigned short* __restrict__ McatT, float* __restrict__ cbias) {
    const int oc = blockIdx.x;            // 0..511
    const int hd = oc >> 7, ip = oc & 127;
    const int a = threadIdx.x;            // 0..127
    const float* wk = Wk + ip * 128 + hd * 32;
    const float* wq = Wq + a * 128 + hd * 32;
    float s = 0.f;
    for (int jj = 0; jj < 32; jj++) s += wq[jj] * wk[jj];
    McatT[(size_t)oc * 128 + a] = f2bf(s * SCORE_SCALE);
    if (a == 0) {
        float c = 0.f;
        for (int jj = 0; jj < 32; jj++) c += bq[hd * 32 + jj] * wk[jj];
        cbias[oc] = c * SCORE_SCALE;
    }
}

__global__ void pcat_kernel(const float* __restrict__ Wv, const float* __restrict__ Wo,
                            unsigned short* __restrict__ PcatT) {
    const int j = blockIdx.x;             // 0..127
    const int k = threadIdx.x;            // 0..511
    const int hd = k >> 7, i = k & 127;
    float s = 0.f;
    for (int cc = 0; cc < 32; cc++)
        s += Wv[i * 128 + hd * 32 + cc] * Wo[(hd * 32 + cc) * 128 + j];
    PcatT[(size_t)j * 512 + k] = f2bf(s);
}

__global__ void bias2_kernel(const float* __restrict__ bv, const float* __restrict__ Wo,
                             const float* __restrict__ bo, float* __restrict__ bias2) {
    const int j = threadIdx.x;
    if (j >= 128) return;
    float s = 0.f;
    for (int c = 0; c < 128; c++) s += bv[c] * Wo[c * 128 + j];
    bias2[j] = s + bo[j];
}

__global__ void cvt_bf16(const float* __restrict__ in, unsigned short* __restrict__ out, long n4) {
    long i = (long)blockIdx.x * 256 + threadIdx.x;
    if (i >= n4) return;
    float4 v = reinterpret_cast<const float4*>(in)[i];
    ushort4 o;
    o.x = f2bf(v.x); o.y = f2bf(v.y); o.z = f2bf(v.z); o.w = f2bf(v.w);
    reinterpret_cast<ushort4*>(out)[i] = o;
}

__global__ void prep_f(const float* __restrict__ f, unsigned short* __restrict__ fb,
                       float* __restrict__ f_h, int n4) {
    int i = blockIdx.x * 256 + threadIdx.x;
    if (i >= n4) return;
    float4 v = reinterpret_cast<const float4*>(f)[i];
    reinterpret_cast<float4*>(f_h)[i] = v;
    ushort4 o;
    o.x = f2bf(v.x); o.y = f2bf(v.y); o.z = f2bf(v.z); o.w = f2bf(v.w);
    reinterpret_cast<ushort4*>(fb)[i] = o;
}

// ---------------------------------------------------------------------------
extern "C" void kernel_launch(void* const* d_in, const int* in_sizes, int n_in,
                              void* d_out, int out_size, void* d_ws, size_t ws_size,
                              hipStream_t stream)
{
    const float* f      = (const float*)d_in[0];
    const float* x      = (const float*)d_in[1];
    const int*   src    = (const int*)d_in[2];
    const int*   dst    = (const int*)d_in[3];
    const float* Wq     = (const float*)d_in[4];
    const float* bq     = (const float*)d_in[5];
    const float* Wk     = (const float*)d_in[6];
    const float* bk     = (const float*)d_in[7];   // cancels in softmax
    const float* Wv     = (const float*)d_in[8];
    const float* bv     = (const float*)d_in[9];
    const float* Wo     = (const float*)d_in[10];
    const float* bo     = (const float*)d_in[11];
    const float* W_mp   = (const float*)d_in[12];
    const float* b_mp   = (const float*)d_in[13];
    const float* W_last = (const float*)d_in[14];
    const float* b_last = (const float*)d_in[15];
    (void)bk;

    const int N = in_sizes[0] / 128;
    const int E = in_sizes[1] / 128;

    char* p = (char*)d_ws;
    auto take = [&](size_t bytes) { char* r = p; p += (bytes + 255) & ~(size_t)255; return r; };
    unsigned short* w5T   = (unsigned short*)take(5 * 16384 * 2);
    unsigned short* McatT = (unsigned short*)take(512 * 128 * 2);
    unsigned short* PcatT = (unsigned short*)take(128 * 512 * 2);
    float* cbias  = (float*)take(512 * 4);
    float* bias2  = (float*)take(128 * 4);
    unsigned short* xb    = (unsigned short*)take((size_t)E * 128 * 2);
    unsigned short* h1    = (unsigned short*)take((size_t)E * 128 * 2);
    unsigned short* h2    = (unsigned short*)take((size_t)E * 128 * 2);
    unsigned short* fb    = (unsigned short*)take((size_t)N * 128 * 2);
    unsigned short* f_hb  = (unsigned short*)take((size_t)N * 128 * 2);
    unsigned short* qkt   = (unsigned short*)take((size_t)N * 512 * 2);
    unsigned short* whm   = (unsigned short*)take((size_t)N * 512 * 2);
    unsigned short* mailb = (unsigned short*)take((size_t)N * 128 * 2);
    float* f_h    = (float*)take((size_t)N * 128 * 4);
    int* deg      = (int*)take((size_t)N * 4);
    int* rowptr   = (int*)take((size_t)(N + 1) * 4);
    int* cursor   = (int*)take((size_t)N * 4);
    int* eidx     = (int*)take((size_t)E * 4);

    const unsigned short* Wm0T = w5T + 0 * 16384;
    const unsigned short* Wm1T = w5T + 1 * 16384;
    const unsigned short* WL0T = w5T + 2 * 16384;
    const unsigned short* WL1T = w5T + 3 * 16384;
    const unsigned short* WL2T = w5T + 4 * 16384;

    W5 w5;
    w5.p[0] = W_mp; w5.p[1] = W_mp + 16384;
    w5.p[2] = W_last; w5.p[3] = W_last + 16384; w5.p[4] = W_last + 32768;

    // --- setup: weights, folded matrices, bf16 copies, CSR ---
    cvt_wT<<<5, 256, 0, stream>>>(w5, w5T);
    mcat_kernel<<<512, 128, 0, stream>>>(Wq, Wk, bq, McatT, cbias);
    pcat_kernel<<<128, 512, 0, stream>>>(Wv, Wo, PcatT);
    bias2_kernel<<<1, 128, 0, stream>>>(bv, Wo, bo, bias2);
    cvt_bf16<<<(int)(((long)E * 32 + 255) / 256), 256, 0, stream>>>(x, xb, (long)E * 32);
    prep_f<<<(N * 32 + 255) / 256, 256, 0, stream>>>(f, fb, f_h, N * 32);

    hipMemsetAsync(deg, 0, (size_t)N * 4, stream);
    hist_kernel<<<(E + 255) / 256, 256, 0, stream>>>(dst, deg, E);
    scan_kernel<<<1, 1024, 0, stream>>>(deg, rowptr, cursor, N);
    scatter_kernel<<<(E + 255) / 256, 256, 0, stream>>>(dst, cursor, eidx, E);

    const int ntN = (N + 63) / 64;
    const int ntE = (E + 63) / 64;
    const int gNode = (N + 3) / 4;
    const int gMrelu = (ntE < 1280) ? ntE : 1280;

    const unsigned short* hc = xb;
    unsigned short* houts[2] = { h1, h2 };
    for (int it = 0; it < 2; it++) {
        const unsigned short* fh_in = (it == 0) ? fb : f_hb;
        // qkt = f_h @ Mcat + c   (bf16 [N,512], log2-scaled scores)
        gemm_q512<<<ntN, 512, 0, stream>>>(fh_in, McatT, cbias, qkt, N);
        // fused attention -> normalized weighted mailbox whm (bf16 [N,512])
        attn_fused<<<gNode, 256, 0, stream>>>(qkt, hc, rowptr, eidx, whm, N);
        // f_h += whm @ Pcat + bias2 ; f_hb = bf16(f_h)
        gemm_k512<<<ntN, 256, 0, stream>>>(whm, PcatT, bias2, f_h, f_hb, N);
        // h' = relu(x + (f_hb[src] - rev(h)) @ Wm + b)
        gemm_mrelu<<<gMrelu, 256, 0, stream>>>(
            f_hb, hc, src, (it == 0) ? Wm0T : Wm1T, b_mp + (size_t)it * 128,
            xb, houts[it], E, ntE);
        hc = houts[it];
    }

    // mail = segment_sum(h, dst)
    mail_csr<<<gNode, 256, 0, stream>>>(hc, rowptr, eidx, mailb, N);

    // out = [mail | f_h | f] @ [WL0;WL1;WL2] + b_last  (one fused GEMM)
    gemm_final<<<ntN, 256, 0, stream>>>(
        mailb, f_hb, fb, WL0T, WL1T, WL2T, b_last, (float*)d_out, N);
}